// Round 9
// baseline (277.571 us; speedup 1.0000x reference)
//
#include <hip/hip_runtime.h>
#include <stdint.h>

typedef float  f32x4  __attribute__((ext_vector_type(4)));
typedef float  float4v __attribute__((ext_vector_type(4)));
typedef int    i32x4  __attribute__((ext_vector_type(4)));
typedef int    i32x8  __attribute__((ext_vector_type(8)));
typedef unsigned int u32x4 __attribute__((ext_vector_type(4)));

#define BM 256
#define BN 256
#define BKB 128   // fp8 bytes (=elements) per K-tile

// ---- f32 (pre-clamped to [-448,448]) -> OCP e4m3fn byte, RNE (matches ml_dtypes) ----
__device__ __forceinline__ unsigned f32_to_e4m3(float t) {
    unsigned u = __float_as_uint(t);
    unsigned s = (u >> 24) & 0x80u;
    float ax = fabsf(t);
    if (ax < 0.015625f) {                      // subnormal grid 2^-9
        int m = (int)rintf(ax * 512.0f);
        return s | (unsigned)m;
    }
    unsigned au = u & 0x7fffffffu;
    unsigned r = au + 0x7FFFFu + ((au >> 20) & 1u);   // RNE into top-3 mantissa bits
    return s | (((r >> 23) - 120u) << 3) | ((r >> 20) & 7u);
}

__global__ void quant_x_kernel(const float4v* __restrict__ x, u32x4* __restrict__ out,
                               const float* __restrict__ in_scale, long n16) {
    const float inv = 1.0f / in_scale[0];
    long i = (long)blockIdx.x * blockDim.x + threadIdx.x;
    const long stride = (long)gridDim.x * blockDim.x;
    for (; i < n16; i += stride) {
        u32x4 q;
#pragma unroll
        for (int j = 0; j < 4; ++j) {
            float4v v = x[i * 4 + j];
            unsigned p = 0;
#pragma unroll
            for (int e = 0; e < 4; ++e) {
                float t = fminf(fmaxf(v[e] * inv, -448.0f), 448.0f);
                p |= f32_to_e4m3(t) << (8 * e);
            }
            q[j] = p;
        }
        out[i] = q;
    }
}

__global__ void quant_w_kernel(const float4v* __restrict__ w, u32x4* __restrict__ out, long n16) {
    long i = (long)blockIdx.x * blockDim.x + threadIdx.x;
    const long stride = (long)gridDim.x * blockDim.x;
    for (; i < n16; i += stride) {
        u32x4 q;
#pragma unroll
        for (int j = 0; j < 4; ++j) {
            float4v v = w[i * 4 + j];
            unsigned p = 0;
#pragma unroll
            for (int e = 0; e < 4; ++e) p |= f32_to_e4m3(v[e]) << (8 * e);
            q[j] = p;
        }
        out[i] = q;
    }
}

// ===== 256x256 fp8 GEMM, 4-phase/K-tile role-split schedule (m201 mechanism) =====
// 8 waves (2M x 4N), per-wave 128x64 (acc[8][4]). LDS 2 x (A 32K + B 32K) = 128 KB.
// __launch_bounds__(512,1): 256-VGPR budget (R8's (512,2) capped at 128 -> acc spilled;
// LDS already limits to 1 block/CU, so the cap bought nothing).

__global__ __launch_bounds__(512, 1) void gemm_kernel(
    const unsigned char* __restrict__ A,   // [M,K] e4m3 bytes
    const unsigned char* __restrict__ W,   // [N,K] e4m3 bytes
    const float* __restrict__ bias,
    const float* __restrict__ in_scale,
    const float* __restrict__ w_scale,
    float* __restrict__ C, int M, int N, int K)
{
    __shared__ __align__(16) unsigned char sA[2][BM * BKB];  // 2 x 32 KB
    __shared__ __align__(16) unsigned char sB[2][BN * BKB];  // 2 x 32 KB

    const int tid  = threadIdx.x;
    const int wave = tid >> 6;     // 0..7
    const int lane = tid & 63;
    const int wr   = wave >> 2;    // 0..1 (M half, 128 rows)
    const int wc   = wave & 3;     // 0..3 (N quarter, 64 cols)

    // XCD-aware bijective swizzle (512 % 8 == 0)
    const int nwg = gridDim.x;
    int bid = blockIdx.x, wgid;
    if ((nwg & 7) == 0) { const int cpx = nwg >> 3; wgid = (bid & 7) * cpx + (bid >> 3); }
    else wgid = bid;
    const int ntn  = N / BN;
    const int brow = (wgid / ntn) * BM;
    const int bcol = (wgid % ntn) * BN;

    // staging: 32 chunks of 1KB per operand (8 rows x 128B); wave stages chunks 4w..4w+3
    // phys 16B-slot (lane&7) holds logical slot (lane&7)^(lane>>3) (pre-swizzled source)
    const int rowInChunk = lane >> 3;
    const int slotLog    = (lane & 7) ^ rowInChunk;

    f32x4 acc[8][4];
#pragma unroll
    for (int i = 0; i < 8; ++i)
#pragma unroll
        for (int j = 0; j < 4; ++j) { f32x4 z = {0.f,0.f,0.f,0.f}; acc[i][j] = z; }

    const int g = lane >> 4;       // k-group: covers k bytes [g*32, g*32+32)

    const int NT = K / BKB;        // 32

    // one issue-round: A chunk (wave*4+c) + B chunk (wave*4+c) of tile t -> buf bi
#define STAGE_RD(bi, t, c)                                                        \
    {                                                                             \
        const int chunk = wave * 4 + (c);                                         \
        const int row   = chunk * 8 + rowInChunk;                                 \
        const unsigned char* ga = A + (long)(brow + row) * K + (t) * BKB + slotLog * 16; \
        const unsigned char* gb = W + (long)(bcol + row) * K + (t) * BKB + slotLog * 16; \
        __builtin_amdgcn_global_load_lds(                                         \
            (const __attribute__((address_space(1))) unsigned int*)ga,            \
            (__attribute__((address_space(3))) unsigned int*)(sA[bi] + chunk * 1024), 16, 0, 0); \
        __builtin_amdgcn_global_load_lds(                                         \
            (const __attribute__((address_space(1))) unsigned int*)gb,            \
            (__attribute__((address_space(3))) unsigned int*)(sB[bi] + chunk * 1024), 16, 0, 0); \
    }

#define FRAG_READ(dst, base, rowexpr)                                             \
    {                                                                             \
        const int row = (rowexpr);                                                \
        const int s0  = (g << 1) ^ (row & 7);                                     \
        i32x4 lo = *(const i32x4*)((base) + row * 128 + s0 * 16);                 \
        i32x4 hi = *(const i32x4*)((base) + row * 128 + (s0 ^ 1) * 16);           \
        i32x8 tv;                                                                 \
        tv[0]=lo[0]; tv[1]=lo[1]; tv[2]=lo[2]; tv[3]=lo[3];                       \
        tv[4]=hi[0]; tv[5]=hi[1]; tv[6]=hi[2]; tv[7]=hi[3];                       \
        dst = tv;                                                                 \
    }

    // prologue: stage tile 0 fully (4 rounds)
#pragma unroll
    for (int c = 0; c < 4; ++c) STAGE_RD(0, 0, c)

    for (int t = 0; t < NT; ++t) {
        const int b = t & 1;
        const unsigned char* sAb = sA[b];
        const unsigned char* sBb = sB[b];
        i32x8 bf[4];

#pragma unroll
        for (int p = 0; p < 4; ++p) {
            if (p == 0) {
                // tile-top fence: issue next tile's round 0 first, then counted drain
                if (t + 1 < NT) {
                    STAGE_RD(b ^ 1, t + 1, 0)
                    asm volatile("s_waitcnt vmcnt(2)" ::: "memory");
                } else {
                    asm volatile("s_waitcnt vmcnt(0)" ::: "memory");
                }
                __builtin_amdgcn_s_barrier();   // all waves' tile-t chunks visible
#pragma unroll
                for (int ni = 0; ni < 4; ++ni)
                    FRAG_READ(bf[ni], sBb, wc * 64 + ni * 16 + (lane & 15))
            } else {
                if (t + 1 < NT) STAGE_RD(b ^ 1, t + 1, p)
            }

            i32x8 a0, a1;
            FRAG_READ(a0, sAb, wr * 128 + (2 * p    ) * 16 + (lane & 15))
            FRAG_READ(a1, sAb, wr * 128 + (2 * p + 1) * 16 + (lane & 15))

            if (p > 0) __builtin_amdgcn_s_barrier();   // phase alignment (pre-MFMA)

            __builtin_amdgcn_s_setprio(1);
#pragma unroll
            for (int ni = 0; ni < 4; ++ni)
                acc[2 * p][ni] = __builtin_amdgcn_mfma_scale_f32_16x16x128_f8f6f4(
                    a0, bf[ni], acc[2 * p][ni], 0, 0, 0, 0x7F7F7F7F, 0, 0x7F7F7F7F);
#pragma unroll
            for (int ni = 0; ni < 4; ++ni)
                acc[2 * p + 1][ni] = __builtin_amdgcn_mfma_scale_f32_16x16x128_f8f6f4(
                    a1, bf[ni], acc[2 * p + 1][ni], 0, 0, 0, 0x7F7F7F7F, 0, 0x7F7F7F7F);
            __builtin_amdgcn_s_setprio(0);
            __builtin_amdgcn_s_barrier();              // phase close
        }
    }
#undef STAGE_RD
#undef FRAG_READ

    // epilogue: out = acc * (s_in*s_w) + bias   (C/D: col=lane&15, row=(lane>>4)*4+r)
    const float sc = in_scale[0] * w_scale[0];
#pragma unroll
    for (int ni = 0; ni < 4; ++ni) {
        const int n   = bcol + wc * 64 + ni * 16 + (lane & 15);
        const float bv = bias[n];
#pragma unroll
        for (int mi = 0; mi < 8; ++mi) {
            const int m0 = brow + wr * 128 + mi * 16 + ((lane >> 4) << 2);
#pragma unroll
            for (int r = 0; r < 4; ++r)
                C[(long)(m0 + r) * N + n] = fmaf(acc[mi][ni][r], sc, bv);
        }
    }
}

extern "C" void kernel_launch(void* const* d_in, const int* in_sizes, int n_in,
                              void* d_out, int out_size, void* d_ws, size_t ws_size,
                              hipStream_t stream) {
    const float* x    = (const float*)d_in[0];   // [B,S,IN] f32
    const float* w    = (const float*)d_in[1];   // [OUT,IN] f32 (e4m3-exact values)
    const float* bias = (const float*)d_in[2];   // [OUT]
    const float* in_s = (const float*)d_in[3];   // [1]
    const float* w_s  = (const float*)d_in[4];   // [1]
    float* out = (float*)d_out;                  // [B,S,OUT]

    const int  N   = in_sizes[2];                // 4096
    const long wsz = (long)in_sizes[1];
    const int  K   = (int)(wsz / N);             // 4096
    const long xsz = (long)in_sizes[0];
    const int  M   = (int)(xsz / K);             // 8192

    unsigned char* xq = (unsigned char*)d_ws;    // M*K e4m3 bytes
    unsigned char* wq = xq + (size_t)M * K;      // N*K e4m3 bytes

    quant_x_kernel<<<2048, 256, 0, stream>>>((const float4v*)x, (u32x4*)xq, in_s, xsz / 16);
    quant_w_kernel<<<2048, 256, 0, stream>>>((const float4v*)w, (u32x4*)wq, wsz / 16);

    dim3 grid((M / BM) * (N / BN));              // 32*16 = 512 blocks, %8==0
    gemm_kernel<<<grid, 512, 0, stream>>>(xq, wq, bias, in_s, w_s, out, M, N, K);
}

// Round 10
// 245.377 us; speedup vs baseline: 1.1312x; 1.1312x over previous
//
#include <hip/hip_runtime.h>
#include <stdint.h>

typedef float  f32x4  __attribute__((ext_vector_type(4)));
typedef float  float4v __attribute__((ext_vector_type(4)));
typedef int    i32x4  __attribute__((ext_vector_type(4)));
typedef int    i32x8  __attribute__((ext_vector_type(8)));
typedef unsigned int u32x4 __attribute__((ext_vector_type(4)));

#define BM 128
#define BN 128
#define BKB 128   // fp8 bytes (=elements) per K-tile

// ---- f32 (pre-clamped to [-448,448]) -> OCP e4m3fn byte, RNE (matches ml_dtypes) ----
__device__ __forceinline__ unsigned f32_to_e4m3(float t) {
    unsigned u = __float_as_uint(t);
    unsigned s = (u >> 24) & 0x80u;
    float ax = fabsf(t);
    if (ax < 0.015625f) {                      // subnormal grid 2^-9
        int m = (int)rintf(ax * 512.0f);
        return s | (unsigned)m;
    }
    unsigned au = u & 0x7fffffffu;
    unsigned r = au + 0x7FFFFu + ((au >> 20) & 1u);   // RNE into top-3 mantissa bits
    return s | (((r >> 23) - 120u) << 3) | ((r >> 20) & 7u);
}

__global__ void quant_x_kernel(const float4v* __restrict__ x, u32x4* __restrict__ out,
                               const float* __restrict__ in_scale, long n16) {
    const float inv = 1.0f / in_scale[0];
    long i = (long)blockIdx.x * blockDim.x + threadIdx.x;
    const long stride = (long)gridDim.x * blockDim.x;
    for (; i < n16; i += stride) {
        u32x4 q;
#pragma unroll
        for (int j = 0; j < 4; ++j) {
            float4v v = x[i * 4 + j];
            unsigned p = 0;
#pragma unroll
            for (int e = 0; e < 4; ++e) {
                float t = fminf(fmaxf(v[e] * inv, -448.0f), 448.0f);
                p |= f32_to_e4m3(t) << (8 * e);
            }
            q[j] = p;
        }
        out[i] = q;
    }
}

__global__ void quant_w_kernel(const float4v* __restrict__ w, u32x4* __restrict__ out, long n16) {
    long i = (long)blockIdx.x * blockDim.x + threadIdx.x;
    const long stride = (long)gridDim.x * blockDim.x;
    for (; i < n16; i += stride) {
        u32x4 q;
#pragma unroll
        for (int j = 0; j < 4; ++j) {
            float4v v = w[i * 4 + j];
            unsigned p = 0;
#pragma unroll
            for (int e = 0; e < 4; ++e) p |= f32_to_e4m3(v[e]) << (8 * e);
            q[j] = p;
        }
        out[i] = q;
    }
}

// ===== 128x128 fp8 GEMM, T3-minimum pipeline (catalog recipe, m248v2) =====
// R4 geometry verbatim; ONE change: double-buffered LDS with STAGE(t+1) issued
// BEFORE compute(t), so the end-of-iter vmcnt(0) drain is covered by the
// compute phase instead of R4's zero-cover drain. 64 KB LDS -> 2 blocks/CU.

__global__ __launch_bounds__(256, 2) void gemm_kernel(
    const unsigned char* __restrict__ A,   // [M,K] e4m3 bytes
    const unsigned char* __restrict__ W,   // [N,K] e4m3 bytes
    const float* __restrict__ bias,
    const float* __restrict__ in_scale,
    const float* __restrict__ w_scale,
    float* __restrict__ C, int M, int N, int K)
{
    __shared__ __align__(16) unsigned char sA[2][BM * BKB];  // 2 x 16 KB
    __shared__ __align__(16) unsigned char sB[2][BN * BKB];  // 2 x 16 KB

    const int tid  = threadIdx.x;
    const int wave = tid >> 6;
    const int lane = tid & 63;
    const int wr   = wave >> 1;
    const int wc   = wave & 1;

    // XCD-aware bijective swizzle (2048 % 8 == 0)
    const int nwg = gridDim.x;
    int bid = blockIdx.x, wgid;
    if ((nwg & 7) == 0) { const int cpx = nwg >> 3; wgid = (bid & 7) * cpx + (bid >> 3); }
    else wgid = bid;
    const int ntn  = N / BN;
    const int brow = (wgid / ntn) * BM;
    const int bcol = (wgid % ntn) * BN;

    // staging: 16 chunks of 1KB per operand-tile (8 rows x 128B); wave stages 4 chunks each
    // phys 16B-slot (lane&7) holds logical slot (lane&7)^(lane>>3) (pre-swizzled source)
    const int rowInChunk = lane >> 3;
    const int slotLog    = (lane & 7) ^ rowInChunk;

    f32x4 acc[4][4];
#pragma unroll
    for (int i = 0; i < 4; ++i)
#pragma unroll
        for (int j = 0; j < 4; ++j) { f32x4 z = {0.f,0.f,0.f,0.f}; acc[i][j] = z; }

    const int g = lane >> 4;   // k-group: covers k bytes [g*32, g*32+32)

    const int NT = K / BKB;    // 32

#define STAGE(bi, t)                                                              \
    {                                                                             \
        const int kt = (t) * BKB;                                                 \
        _Pragma("unroll")                                                         \
        for (int c = 0; c < 4; ++c) {                                             \
            const int chunk = wave * 4 + c;                                       \
            const int row   = chunk * 8 + rowInChunk;                             \
            const unsigned char* ga = A + (long)(brow + row) * K + kt + slotLog * 16; \
            const unsigned char* gb = W + (long)(bcol + row) * K + kt + slotLog * 16; \
            __builtin_amdgcn_global_load_lds(                                     \
                (const __attribute__((address_space(1))) unsigned int*)ga,        \
                (__attribute__((address_space(3))) unsigned int*)(sA[bi] + chunk * 1024), 16, 0, 0); \
            __builtin_amdgcn_global_load_lds(                                     \
                (const __attribute__((address_space(1))) unsigned int*)gb,        \
                (__attribute__((address_space(3))) unsigned int*)(sB[bi] + chunk * 1024), 16, 0, 0); \
        }                                                                         \
    }

#define FRAG_READ(dst, base, rowexpr)                                             \
    {                                                                             \
        const int row = (rowexpr);                                                \
        const int s0  = (g << 1) ^ (row & 7);                                     \
        i32x4 lo = *(const i32x4*)((base) + row * 128 + s0 * 16);                 \
        i32x4 hi = *(const i32x4*)((base) + row * 128 + (s0 ^ 1) * 16);           \
        i32x8 tv;                                                                 \
        tv[0]=lo[0]; tv[1]=lo[1]; tv[2]=lo[2]; tv[3]=lo[3];                       \
        tv[4]=hi[0]; tv[5]=hi[1]; tv[6]=hi[2]; tv[7]=hi[3];                       \
        dst = tv;                                                                 \
    }

    // prologue: tile 0 -> buf0, full drain (nothing to cover it yet)
    STAGE(0, 0);
    asm volatile("s_waitcnt vmcnt(0)" ::: "memory");
    __builtin_amdgcn_s_barrier();

    int cur = 0;
    for (int t = 0; t < NT; ++t) {
        if (t + 1 < NT) STAGE(cur ^ 1, t + 1);     // issue EARLY: flies during compute

        i32x8 af[4], bfr[4];
#pragma unroll
        for (int mi = 0; mi < 4; ++mi)
            FRAG_READ(af[mi], sA[cur], wr * 64 + mi * 16 + (lane & 15))
#pragma unroll
        for (int ni = 0; ni < 4; ++ni)
            FRAG_READ(bfr[ni], sB[cur], wc * 64 + ni * 16 + (lane & 15))

        asm volatile("s_waitcnt lgkmcnt(0)" ::: "memory");   // my reads of buf[cur] done
        __builtin_amdgcn_sched_barrier(0);                    // rule #18: no MFMA hoist

#pragma unroll
        for (int mi = 0; mi < 4; ++mi)
#pragma unroll
            for (int ni = 0; ni < 4; ++ni)
                acc[mi][ni] = __builtin_amdgcn_mfma_scale_f32_16x16x128_f8f6f4(
                    af[mi], bfr[ni], acc[mi][ni], 0, 0, 0, 0x7F7F7F7F, 0, 0x7F7F7F7F);

        if (t + 1 < NT) {
            asm volatile("s_waitcnt vmcnt(0)" ::: "memory");  // covered drain: t+1 landed
            __builtin_amdgcn_s_barrier();                      // all reads of buf[cur] done too
            cur ^= 1;
        }
    }
#undef STAGE
#undef FRAG_READ

    // epilogue: out = acc * (s_in*s_w) + bias   (C/D: col=lane&15, row=(lane>>4)*4+r)
    const float sc = in_scale[0] * w_scale[0];
#pragma unroll
    for (int ni = 0; ni < 4; ++ni) {
        const int n   = bcol + wc * 64 + ni * 16 + (lane & 15);
        const float bv = bias[n];
#pragma unroll
        for (int mi = 0; mi < 4; ++mi) {
            const int m0 = brow + wr * 64 + mi * 16 + ((lane >> 4) << 2);
#pragma unroll
            for (int r = 0; r < 4; ++r)
                C[(long)(m0 + r) * N + n] = fmaf(acc[mi][ni][r], sc, bv);
        }
    }
}

extern "C" void kernel_launch(void* const* d_in, const int* in_sizes, int n_in,
                              void* d_out, int out_size, void* d_ws, size_t ws_size,
                              hipStream_t stream) {
    const float* x    = (const float*)d_in[0];   // [B,S,IN] f32
    const float* w    = (const float*)d_in[1];   // [OUT,IN] f32 (e4m3-exact values)
    const float* bias = (const float*)d_in[2];   // [OUT]
    const float* in_s = (const float*)d_in[3];   // [1]
    const float* w_s  = (const float*)d_in[4];   // [1]
    float* out = (float*)d_out;                  // [B,S,OUT]

    const int  N   = in_sizes[2];                // 4096
    const long wsz = (long)in_sizes[1];
    const int  K   = (int)(wsz / N);             // 4096
    const long xsz = (long)in_sizes[0];
    const int  M   = (int)(xsz / K);             // 8192

    unsigned char* xq = (unsigned char*)d_ws;    // M*K e4m3 bytes
    unsigned char* wq = xq + (size_t)M * K;      // N*K e4m3 bytes

    quant_x_kernel<<<2048, 256, 0, stream>>>((const float4v*)x, (u32x4*)xq, in_s, xsz / 16);
    quant_w_kernel<<<2048, 256, 0, stream>>>((const float4v*)w, (u32x4*)wq, wsz / 16);

    dim3 grid((M / BM) * (N / BN));              // 64*32 = 2048 blocks, %8==0
    gemm_kernel<<<grid, 256, 0, stream>>>(xq, wq, bias, in_s, w_s, out, M, N, K);
}

// Round 11
// 208.748 us; speedup vs baseline: 1.3297x; 1.1755x over previous
//
#include <hip/hip_runtime.h>
#include <stdint.h>

typedef float  f32x4  __attribute__((ext_vector_type(4)));
typedef float  float4v __attribute__((ext_vector_type(4)));
typedef int    i32x4  __attribute__((ext_vector_type(4)));
typedef int    i32x8  __attribute__((ext_vector_type(8)));
typedef unsigned int u32x4 __attribute__((ext_vector_type(4)));

#define BM 128
#define BN 128
#define BKB 128   // fp8 bytes (=elements) per K-tile

// ---- f32 (pre-clamped to [-448,448]) -> OCP e4m3fn byte, RNE (matches ml_dtypes) ----
__device__ __forceinline__ unsigned f32_to_e4m3(float t) {
    unsigned u = __float_as_uint(t);
    unsigned s = (u >> 24) & 0x80u;
    float ax = fabsf(t);
    if (ax < 0.015625f) {                      // subnormal grid 2^-9
        int m = (int)rintf(ax * 512.0f);
        return s | (unsigned)m;
    }
    unsigned au = u & 0x7fffffffu;
    unsigned r = au + 0x7FFFFu + ((au >> 20) & 1u);   // RNE into top-3 mantissa bits
    return s | (((r >> 23) - 120u) << 3) | ((r >> 20) & 7u);
}

__global__ void quant_x_kernel(const float4v* __restrict__ x, u32x4* __restrict__ out,
                               const float* __restrict__ in_scale, long n16) {
    const float inv = 1.0f / in_scale[0];
    long i = (long)blockIdx.x * blockDim.x + threadIdx.x;
    const long stride = (long)gridDim.x * blockDim.x;
    for (; i < n16; i += stride) {
        u32x4 q;
#pragma unroll
        for (int j = 0; j < 4; ++j) {
            float4v v = x[i * 4 + j];
            unsigned p = 0;
#pragma unroll
            for (int e = 0; e < 4; ++e) {
                float t = fminf(fmaxf(v[e] * inv, -448.0f), 448.0f);
                p |= f32_to_e4m3(t) << (8 * e);
            }
            q[j] = p;
        }
        out[i] = q;
    }
}

__global__ void quant_w_kernel(const float4v* __restrict__ w, u32x4* __restrict__ out, long n16) {
    long i = (long)blockIdx.x * blockDim.x + threadIdx.x;
    const long stride = (long)gridDim.x * blockDim.x;
    for (; i < n16; i += stride) {
        u32x4 q;
#pragma unroll
        for (int j = 0; j < 4; ++j) {
            float4v v = w[i * 4 + j];
            unsigned p = 0;
#pragma unroll
            for (int e = 0; e < 4; ++e) p |= f32_to_e4m3(v[e]) << (8 * e);
            q[j] = p;
        }
        out[i] = q;
    }
}

// ===== R4 kernel (best: 158 us) + sigma-permuted granule order =====
// Store k-granule j of each row at slot pi(j) = (j>>1) + 4*(j&1), still XOR'd
// with (row&7). Lane g then reads its granules 2g,2g+1 at slots g^sw and
// (g^sw)^4 -- the bf16-R3 slot distribution that measured ZERO bank conflicts
// (vs R4's (2g)^sw dual-slot pattern: measured +4 cyc per ds_read_b128).

__global__ __launch_bounds__(256, 2) void gemm_kernel(
    const unsigned char* __restrict__ A,   // [M,K] e4m3 bytes
    const unsigned char* __restrict__ W,   // [N,K] e4m3 bytes
    const float* __restrict__ bias,
    const float* __restrict__ in_scale,
    const float* __restrict__ w_scale,
    float* __restrict__ C, int M, int N, int K)
{
    __shared__ __align__(16) unsigned char sA[BM * BKB];  // 16 KB
    __shared__ __align__(16) unsigned char sB[BN * BKB];  // 16 KB

    const int tid  = threadIdx.x;
    const int wave = tid >> 6;
    const int lane = tid & 63;
    const int wr   = wave >> 1;
    const int wc   = wave & 1;

    // XCD-aware bijective swizzle (2048 % 8 == 0)
    const int nwg = gridDim.x;
    int bid = blockIdx.x, wgid;
    if ((nwg & 7) == 0) { const int cpx = nwg >> 3; wgid = (bid & 7) * cpx + (bid >> 3); }
    else wgid = bid;
    const int ntn  = N / BN;
    const int brow = (wgid / ntn) * BM;
    const int bcol = (wgid % ntn) * BN;

    // staging: 16 chunks of 1KB per tile (8 rows x 128B); wave w stages chunks 4w..4w+3
    // phys slot (lane&7) must hold logical granule pi^-1((lane&7) ^ (lane>>3)):
    //   p = (lane&7)^(lane>>3);  slotSrc = 2*(p&3) + (p>>2)
    const int rowInChunk = lane >> 3;
    const int pPhys      = (lane & 7) ^ rowInChunk;
    const int slotSrc    = 2 * (pPhys & 3) + (pPhys >> 2);

    f32x4 acc[4][4];
#pragma unroll
    for (int i = 0; i < 4; ++i)
#pragma unroll
        for (int j = 0; j < 4; ++j) { f32x4 z = {0.f,0.f,0.f,0.f}; acc[i][j] = z; }

    const int g = lane >> 4;   // k-group 0..3: lane covers k bytes [g*32, g*32+32)

    for (int kt = 0; kt < K; kt += BKB) {
        if (kt) __syncthreads();
#pragma unroll
        for (int c = 0; c < 4; ++c) {
            const int chunk = wave * 4 + c;
            const int row   = chunk * 8 + rowInChunk;
            const unsigned char* ga = A + (long)(brow + row) * K + kt + slotSrc * 16;
            const unsigned char* gb = W + (long)(bcol + row) * K + kt + slotSrc * 16;
            __builtin_amdgcn_global_load_lds(
                (const __attribute__((address_space(1))) unsigned int*)ga,
                (__attribute__((address_space(3))) unsigned int*)(sA + chunk * 1024), 16, 0, 0);
            __builtin_amdgcn_global_load_lds(
                (const __attribute__((address_space(1))) unsigned int*)gb,
                (__attribute__((address_space(3))) unsigned int*)(sB + chunk * 1024), 16, 0, 0);
        }
        __syncthreads();

        i32x8 af[4], bfr[4];
#pragma unroll
        for (int mi = 0; mi < 4; ++mi) {
            const int row = wr * 64 + mi * 16 + (lane & 15);
            const int sl  = g ^ (row & 7);          // lo slot: holds granule 2g
            i32x4 lo = *(const i32x4*)(sA + row * 128 + sl * 16);
            i32x4 hi = *(const i32x4*)(sA + row * 128 + (sl ^ 4) * 16);  // granule 2g+1
            i32x8 t;
            t[0]=lo[0]; t[1]=lo[1]; t[2]=lo[2]; t[3]=lo[3];
            t[4]=hi[0]; t[5]=hi[1]; t[6]=hi[2]; t[7]=hi[3];
            af[mi] = t;
        }
#pragma unroll
        for (int ni = 0; ni < 4; ++ni) {
            const int row = wc * 64 + ni * 16 + (lane & 15);
            const int sl  = g ^ (row & 7);
            i32x4 lo = *(const i32x4*)(sB + row * 128 + sl * 16);
            i32x4 hi = *(const i32x4*)(sB + row * 128 + (sl ^ 4) * 16);
            i32x8 t;
            t[0]=lo[0]; t[1]=lo[1]; t[2]=lo[2]; t[3]=lo[3];
            t[4]=hi[0]; t[5]=hi[1]; t[6]=hi[2]; t[7]=hi[3];
            bfr[ni] = t;
        }

#pragma unroll
        for (int mi = 0; mi < 4; ++mi)
#pragma unroll
            for (int ni = 0; ni < 4; ++ni)
                acc[mi][ni] = __builtin_amdgcn_mfma_scale_f32_16x16x128_f8f6f4(
                    af[mi], bfr[ni], acc[mi][ni],
                    0, 0, 0, 0x7F7F7F7F, 0, 0x7F7F7F7F);
    }

    // epilogue: out = acc * (s_in*s_w) + bias   (C/D: col=lane&15, row=(lane>>4)*4+r)
    const float sc = in_scale[0] * w_scale[0];
#pragma unroll
    for (int ni = 0; ni < 4; ++ni) {
        const int n   = bcol + wc * 64 + ni * 16 + (lane & 15);
        const float bv = bias[n];
#pragma unroll
        for (int mi = 0; mi < 4; ++mi) {
            const int m0 = brow + wr * 64 + mi * 16 + ((lane >> 4) << 2);
#pragma unroll
            for (int r = 0; r < 4; ++r)
                C[(long)(m0 + r) * N + n] = fmaf(acc[mi][ni][r], sc, bv);
        }
    }
}

extern "C" void kernel_launch(void* const* d_in, const int* in_sizes, int n_in,
                              void* d_out, int out_size, void* d_ws, size_t ws_size,
                              hipStream_t stream) {
    const float* x    = (const float*)d_in[0];   // [B,S,IN] f32
    const float* w    = (const float*)d_in[1];   // [OUT,IN] f32 (e4m3-exact values)
    const float* bias = (const float*)d_in[2];   // [OUT]
    const float* in_s = (const float*)d_in[3];   // [1]
    const float* w_s  = (const float*)d_in[4];   // [1]
    float* out = (float*)d_out;                  // [B,S,OUT]

    const int  N   = in_sizes[2];                // 4096
    const long wsz = (long)in_sizes[1];
    const int  K   = (int)(wsz / N);             // 4096
    const long xsz = (long)in_sizes[0];
    const int  M   = (int)(xsz / K);             // 8192

    unsigned char* xq = (unsigned char*)d_ws;    // M*K e4m3 bytes
    unsigned char* wq = xq + (size_t)M * K;      // N*K e4m3 bytes

    quant_x_kernel<<<2048, 256, 0, stream>>>((const float4v*)x, (u32x4*)xq, in_s, xsz / 16);
    quant_w_kernel<<<2048, 256, 0, stream>>>((const float4v*)w, (u32x4*)wq, wsz / 16);

    dim3 grid((M / BM) * (N / BN));              // 64*32 = 2048 blocks, %8==0
    gemm_kernel<<<grid, 256, 0, stream>>>(xq, wq, bias, in_s, w_s, out, M, N, K);
}

// Round 12
// 206.644 us; speedup vs baseline: 1.3432x; 1.0102x over previous
//
#include <hip/hip_runtime.h>
#include <stdint.h>

typedef float  f32x4  __attribute__((ext_vector_type(4)));
typedef float  float4v __attribute__((ext_vector_type(4)));
typedef int    i32x4  __attribute__((ext_vector_type(4)));
typedef int    i32x8  __attribute__((ext_vector_type(8)));
typedef unsigned int u32x4 __attribute__((ext_vector_type(4)));

#define BM 128
#define BN 128
#define BKB 128   // fp8 bytes (=elements) per K-tile

// ---- f32 (pre-clamped to [-448,448]) -> OCP e4m3fn byte, RNE (matches ml_dtypes) ----
__device__ __forceinline__ unsigned f32_to_e4m3(float t) {
    unsigned u = __float_as_uint(t);
    unsigned s = (u >> 24) & 0x80u;
    float ax = fabsf(t);
    if (ax < 0.015625f) {                      // subnormal grid 2^-9
        int m = (int)rintf(ax * 512.0f);
        return s | (unsigned)m;
    }
    unsigned au = u & 0x7fffffffu;
    unsigned r = au + 0x7FFFFu + ((au >> 20) & 1u);   // RNE into top-3 mantissa bits
    return s | (((r >> 23) - 120u) << 3) | ((r >> 20) & 7u);
}

// ---- merged quant: x (scale+clamp+round) then w (exact convert), one launch ----
__global__ void quant_kernel(const float4v* __restrict__ x, u32x4* __restrict__ xout, long nx16,
                             const float4v* __restrict__ w, u32x4* __restrict__ wout, long nw16,
                             const float* __restrict__ in_scale) {
    const float inv = 1.0f / in_scale[0];
    const long stride = (long)gridDim.x * blockDim.x;
    long i0 = (long)blockIdx.x * blockDim.x + threadIdx.x;
    for (long i = i0; i < nx16; i += stride) {
        u32x4 q;
#pragma unroll
        for (int j = 0; j < 4; ++j) {
            float4v v = x[i * 4 + j];
            unsigned p = 0;
#pragma unroll
            for (int e = 0; e < 4; ++e) {
                float t = fminf(fmaxf(v[e] * inv, -448.0f), 448.0f);
                p |= f32_to_e4m3(t) << (8 * e);
            }
            q[j] = p;
        }
        xout[i] = q;
    }
    for (long i = i0; i < nw16; i += stride) {
        u32x4 q;
#pragma unroll
        for (int j = 0; j < 4; ++j) {
            float4v v = w[i * 4 + j];
            unsigned p = 0;
#pragma unroll
            for (int e = 0; e < 4; ++e) p |= f32_to_e4m3(v[e]) << (8 * e);
            q[j] = p;
        }
        wout[i] = q;
    }
}

// ===== R11 kernel (best: 150 us, 0 bank conflicts) + occupancy 2->3 blocks/CU =====
// sigma-permuted granule order: slot pi(j) = (j>>1)+4*(j&1), XOR'd with row&7.
// Lane g reads granules 2g,2g+1 at slots g^sw, (g^sw)^4 (measured 0 conflicts).
// __launch_bounds__(256,3): 12 waves/CU -- m114 cross-block overlap absorbs the
// barrier drain that caps MfmaUtil at 40% with only 2 blocks/CU.

__global__ __launch_bounds__(256, 3) void gemm_kernel(
    const unsigned char* __restrict__ A,   // [M,K] e4m3 bytes
    const unsigned char* __restrict__ W,   // [N,K] e4m3 bytes
    const float* __restrict__ bias,
    const float* __restrict__ in_scale,
    const float* __restrict__ w_scale,
    float* __restrict__ C, int M, int N, int K)
{
    __shared__ __align__(16) unsigned char sA[BM * BKB];  // 16 KB
    __shared__ __align__(16) unsigned char sB[BN * BKB];  // 16 KB

    const int tid  = threadIdx.x;
    const int wave = tid >> 6;
    const int lane = tid & 63;
    const int wr   = wave >> 1;
    const int wc   = wave & 1;

    // XCD-aware bijective swizzle (2048 % 8 == 0)
    const int nwg = gridDim.x;
    int bid = blockIdx.x, wgid;
    if ((nwg & 7) == 0) { const int cpx = nwg >> 3; wgid = (bid & 7) * cpx + (bid >> 3); }
    else wgid = bid;
    const int ntn  = N / BN;
    const int brow = (wgid / ntn) * BM;
    const int bcol = (wgid % ntn) * BN;

    // staging: phys slot (lane&7) holds granule pi^-1((lane&7)^(lane>>3)):
    //   p = (lane&7)^(lane>>3);  slotSrc = 2*(p&3) + (p>>2)
    const int rowInChunk = lane >> 3;
    const int pPhys      = (lane & 7) ^ rowInChunk;
    const int slotSrc    = 2 * (pPhys & 3) + (pPhys >> 2);

    f32x4 acc[4][4];
#pragma unroll
    for (int i = 0; i < 4; ++i)
#pragma unroll
        for (int j = 0; j < 4; ++j) { f32x4 z = {0.f,0.f,0.f,0.f}; acc[i][j] = z; }

    const int g = lane >> 4;   // k-group 0..3: lane covers k bytes [g*32, g*32+32)

    for (int kt = 0; kt < K; kt += BKB) {
        if (kt) __syncthreads();
#pragma unroll
        for (int c = 0; c < 4; ++c) {
            const int chunk = wave * 4 + c;
            const int row   = chunk * 8 + rowInChunk;
            const unsigned char* ga = A + (long)(brow + row) * K + kt + slotSrc * 16;
            const unsigned char* gb = W + (long)(bcol + row) * K + kt + slotSrc * 16;
            __builtin_amdgcn_global_load_lds(
                (const __attribute__((address_space(1))) unsigned int*)ga,
                (__attribute__((address_space(3))) unsigned int*)(sA + chunk * 1024), 16, 0, 0);
            __builtin_amdgcn_global_load_lds(
                (const __attribute__((address_space(1))) unsigned int*)gb,
                (__attribute__((address_space(3))) unsigned int*)(sB + chunk * 1024), 16, 0, 0);
        }
        __syncthreads();

        i32x8 af[4], bfr[4];
#pragma unroll
        for (int mi = 0; mi < 4; ++mi) {
            const int row = wr * 64 + mi * 16 + (lane & 15);
            const int sl  = g ^ (row & 7);          // lo slot: granule 2g
            i32x4 lo = *(const i32x4*)(sA + row * 128 + sl * 16);
            i32x4 hi = *(const i32x4*)(sA + row * 128 + (sl ^ 4) * 16);  // granule 2g+1
            i32x8 t;
            t[0]=lo[0]; t[1]=lo[1]; t[2]=lo[2]; t[3]=lo[3];
            t[4]=hi[0]; t[5]=hi[1]; t[6]=hi[2]; t[7]=hi[3];
            af[mi] = t;
        }
#pragma unroll
        for (int ni = 0; ni < 4; ++ni) {
            const int row = wc * 64 + ni * 16 + (lane & 15);
            const int sl  = g ^ (row & 7);
            i32x4 lo = *(const i32x4*)(sB + row * 128 + sl * 16);
            i32x4 hi = *(const i32x4*)(sB + row * 128 + (sl ^ 4) * 16);
            i32x8 t;
            t[0]=lo[0]; t[1]=lo[1]; t[2]=lo[2]; t[3]=lo[3];
            t[4]=hi[0]; t[5]=hi[1]; t[6]=hi[2]; t[7]=hi[3];
            bfr[ni] = t;
        }

#pragma unroll
        for (int mi = 0; mi < 4; ++mi)
#pragma unroll
            for (int ni = 0; ni < 4; ++ni)
                acc[mi][ni] = __builtin_amdgcn_mfma_scale_f32_16x16x128_f8f6f4(
                    af[mi], bfr[ni], acc[mi][ni],
                    0, 0, 0, 0x7F7F7F7F, 0, 0x7F7F7F7F);
    }

    // epilogue: out = acc * (s_in*s_w) + bias   (C/D: col=lane&15, row=(lane>>4)*4+r)
    const float sc = in_scale[0] * w_scale[0];
#pragma unroll
    for (int ni = 0; ni < 4; ++ni) {
        const int n   = bcol + wc * 64 + ni * 16 + (lane & 15);
        const float bv = bias[n];
#pragma unroll
        for (int mi = 0; mi < 4; ++mi) {
            const int m0 = brow + wr * 64 + mi * 16 + ((lane >> 4) << 2);
#pragma unroll
            for (int r = 0; r < 4; ++r)
                C[(long)(m0 + r) * N + n] = fmaf(acc[mi][ni][r], sc, bv);
        }
    }
}

extern "C" void kernel_launch(void* const* d_in, const int* in_sizes, int n_in,
                              void* d_out, int out_size, void* d_ws, size_t ws_size,
                              hipStream_t stream) {
    const float* x    = (const float*)d_in[0];   // [B,S,IN] f32
    const float* w    = (const float*)d_in[1];   // [OUT,IN] f32 (e4m3-exact values)
    const float* bias = (const float*)d_in[2];   // [OUT]
    const float* in_s = (const float*)d_in[3];   // [1]
    const float* w_s  = (const float*)d_in[4];   // [1]
    float* out = (float*)d_out;                  // [B,S,OUT]

    const int  N   = in_sizes[2];                // 4096
    const long wsz = (long)in_sizes[1];
    const int  K   = (int)(wsz / N);             // 4096
    const long xsz = (long)in_sizes[0];
    const int  M   = (int)(xsz / K);             // 8192

    unsigned char* xq = (unsigned char*)d_ws;    // M*K e4m3 bytes
    unsigned char* wq = xq + (size_t)M * K;      // N*K e4m3 bytes

    quant_kernel<<<2048, 256, 0, stream>>>((const float4v*)x, (u32x4*)xq, xsz / 16,
                                           (const float4v*)w, (u32x4*)wq, wsz / 16, in_s);

    dim3 grid((M / BM) * (N / BN));              // 64*32 = 2048 blocks, %8==0
    gemm_kernel<<<grid, 256, 0, stream>>>(xq, wq, bias, in_s, w_s, out, M, N, K);
}

// Round 13
// 193.078 us; speedup vs baseline: 1.4376x; 1.0703x over previous
//
#include <hip/hip_runtime.h>
#include <stdint.h>

typedef float  f32x4  __attribute__((ext_vector_type(4)));
typedef float  float4v __attribute__((ext_vector_type(4)));
typedef int    i32x4  __attribute__((ext_vector_type(4)));
typedef int    i32x8  __attribute__((ext_vector_type(8)));
typedef unsigned int u32x4 __attribute__((ext_vector_type(4)));

#define BM 128
#define BN 256
#define BKB 128   // fp8 bytes (=elements) per K-tile

// ---- f32 (pre-clamped to [-448,448]) -> OCP e4m3fn byte, RNE (matches ml_dtypes) ----
__device__ __forceinline__ unsigned f32_to_e4m3(float t) {
    unsigned u = __float_as_uint(t);
    unsigned s = (u >> 24) & 0x80u;
    float ax = fabsf(t);
    if (ax < 0.015625f) {                      // subnormal grid 2^-9
        int m = (int)rintf(ax * 512.0f);
        return s | (unsigned)m;
    }
    unsigned au = u & 0x7fffffffu;
    unsigned r = au + 0x7FFFFu + ((au >> 20) & 1u);   // RNE into top-3 mantissa bits
    return s | (((r >> 23) - 120u) << 3) | ((r >> 20) & 7u);
}

// ---- merged quant: x (scale+clamp+round) then w (exact convert), one launch ----
__global__ void quant_kernel(const float4v* __restrict__ x, u32x4* __restrict__ xout, long nx16,
                             const float4v* __restrict__ w, u32x4* __restrict__ wout, long nw16,
                             const float* __restrict__ in_scale) {
    const float inv = 1.0f / in_scale[0];
    const long stride = (long)gridDim.x * blockDim.x;
    long i0 = (long)blockIdx.x * blockDim.x + threadIdx.x;
    for (long i = i0; i < nx16; i += stride) {
        u32x4 q;
#pragma unroll
        for (int j = 0; j < 4; ++j) {
            float4v v = x[i * 4 + j];
            unsigned p = 0;
#pragma unroll
            for (int e = 0; e < 4; ++e) {
                float t = fminf(fmaxf(v[e] * inv, -448.0f), 448.0f);
                p |= f32_to_e4m3(t) << (8 * e);
            }
            q[j] = p;
        }
        xout[i] = q;
    }
    for (long i = i0; i < nw16; i += stride) {
        u32x4 q;
#pragma unroll
        for (int j = 0; j < 4; ++j) {
            float4v v = w[i * 4 + j];
            unsigned p = 0;
#pragma unroll
            for (int e = 0; e < 4; ++e) p |= f32_to_e4m3(v[e]) << (8 * e);
            q[j] = p;
        }
        wout[i] = q;
    }
}

// ===== 128x256 fp8 GEMM: R11 structure (2-barrier, sigma-swizzle, 0 conflicts) =====
// 4 waves (2M x 2N), per-wave 64x128 output: acc[4][8]. LDS A 16K + B 32K = 48 KB
// -> 2 blocks/CU. -25% LDS bytes/MFMA vs 128^2 (reads 48 vs 64 KB per output unit).
// B fragments read one-at-a-time inside the MFMA loop to hold VGPR ~190 < 256.

__global__ __launch_bounds__(256, 2) void gemm_kernel(
    const unsigned char* __restrict__ A,   // [M,K] e4m3 bytes
    const unsigned char* __restrict__ W,   // [N,K] e4m3 bytes
    const float* __restrict__ bias,
    const float* __restrict__ in_scale,
    const float* __restrict__ w_scale,
    float* __restrict__ C, int M, int N, int K)
{
    __shared__ __align__(16) unsigned char sA[BM * BKB];  // 16 KB
    __shared__ __align__(16) unsigned char sB[BN * BKB];  // 32 KB

    const int tid  = threadIdx.x;
    const int wave = tid >> 6;
    const int lane = tid & 63;
    const int wr   = wave >> 1;    // 0..1: rows 64 each
    const int wc   = wave & 1;     // 0..1: cols 128 each

    // XCD-aware bijective swizzle (1024 % 8 == 0)
    const int nwg = gridDim.x;
    int bid = blockIdx.x, wgid;
    if ((nwg & 7) == 0) { const int cpx = nwg >> 3; wgid = (bid & 7) * cpx + (bid >> 3); }
    else wgid = bid;
    const int ntn  = N / BN;
    const int brow = (wgid / ntn) * BM;
    const int bcol = (wgid % ntn) * BN;

    // sigma-swizzled staging (R11, measured 0 conflicts):
    // phys slot (lane&7) holds granule pi^-1((lane&7)^(lane>>3)):
    //   p = (lane&7)^(lane>>3);  slotSrc = 2*(p&3) + (p>>2)
    const int rowInChunk = lane >> 3;
    const int pPhys      = (lane & 7) ^ rowInChunk;
    const int slotSrc    = 2 * (pPhys & 3) + (pPhys >> 2);

    f32x4 acc[4][8];
#pragma unroll
    for (int i = 0; i < 4; ++i)
#pragma unroll
        for (int j = 0; j < 8; ++j) { f32x4 z = {0.f,0.f,0.f,0.f}; acc[i][j] = z; }

    const int g = lane >> 4;   // k-group 0..3: lane covers k bytes [g*32, g*32+32)

    for (int kt = 0; kt < K; kt += BKB) {
        if (kt) __syncthreads();
        // stage A: 16 chunks (4/wave); B: 32 chunks (8/wave). 12 loads/thread.
#pragma unroll
        for (int c = 0; c < 4; ++c) {
            const int chunk = wave * 4 + c;
            const int row   = chunk * 8 + rowInChunk;
            const unsigned char* ga = A + (long)(brow + row) * K + kt + slotSrc * 16;
            __builtin_amdgcn_global_load_lds(
                (const __attribute__((address_space(1))) unsigned int*)ga,
                (__attribute__((address_space(3))) unsigned int*)(sA + chunk * 1024), 16, 0, 0);
        }
#pragma unroll
        for (int c = 0; c < 8; ++c) {
            const int chunk = wave * 8 + c;
            const int row   = chunk * 8 + rowInChunk;
            const unsigned char* gb = W + (long)(bcol + row) * K + kt + slotSrc * 16;
            __builtin_amdgcn_global_load_lds(
                (const __attribute__((address_space(1))) unsigned int*)gb,
                (__attribute__((address_space(3))) unsigned int*)(sB + chunk * 1024), 16, 0, 0);
        }
        __syncthreads();

        i32x8 af[4];
#pragma unroll
        for (int mi = 0; mi < 4; ++mi) {
            const int row = wr * 64 + mi * 16 + (lane & 15);
            const int sl  = g ^ (row & 7);          // lo slot: granule 2g
            i32x4 lo = *(const i32x4*)(sA + row * 128 + sl * 16);
            i32x4 hi = *(const i32x4*)(sA + row * 128 + (sl ^ 4) * 16);  // granule 2g+1
            i32x8 t;
            t[0]=lo[0]; t[1]=lo[1]; t[2]=lo[2]; t[3]=lo[3];
            t[4]=hi[0]; t[5]=hi[1]; t[6]=hi[2]; t[7]=hi[3];
            af[mi] = t;
        }
#pragma unroll
        for (int ni = 0; ni < 8; ++ni) {
            const int row = wc * 128 + ni * 16 + (lane & 15);
            const int sl  = g ^ (row & 7);
            i32x4 lo = *(const i32x4*)(sB + row * 128 + sl * 16);
            i32x4 hi = *(const i32x4*)(sB + row * 128 + (sl ^ 4) * 16);
            i32x8 bf;
            bf[0]=lo[0]; bf[1]=lo[1]; bf[2]=lo[2]; bf[3]=lo[3];
            bf[4]=hi[0]; bf[5]=hi[1]; bf[6]=hi[2]; bf[7]=hi[3];
#pragma unroll
            for (int mi = 0; mi < 4; ++mi)
                acc[mi][ni] = __builtin_amdgcn_mfma_scale_f32_16x16x128_f8f6f4(
                    af[mi], bf, acc[mi][ni],
                    0, 0, 0, 0x7F7F7F7F, 0, 0x7F7F7F7F);
        }
    }

    // epilogue: out = acc * (s_in*s_w) + bias   (C/D: col=lane&15, row=(lane>>4)*4+r)
    const float sc = in_scale[0] * w_scale[0];
#pragma unroll
    for (int ni = 0; ni < 8; ++ni) {
        const int n   = bcol + wc * 128 + ni * 16 + (lane & 15);
        const float bv = bias[n];
#pragma unroll
        for (int mi = 0; mi < 4; ++mi) {
            const int m0 = brow + wr * 64 + mi * 16 + ((lane >> 4) << 2);
#pragma unroll
            for (int r = 0; r < 4; ++r)
                C[(long)(m0 + r) * N + n] = fmaf(acc[mi][ni][r], sc, bv);
        }
    }
}

extern "C" void kernel_launch(void* const* d_in, const int* in_sizes, int n_in,
                              void* d_out, int out_size, void* d_ws, size_t ws_size,
                              hipStream_t stream) {
    const float* x    = (const float*)d_in[0];   // [B,S,IN] f32
    const float* w    = (const float*)d_in[1];   // [OUT,IN] f32 (e4m3-exact values)
    const float* bias = (const float*)d_in[2];   // [OUT]
    const float* in_s = (const float*)d_in[3];   // [1]
    const float* w_s  = (const float*)d_in[4];   // [1]
    float* out = (float*)d_out;                  // [B,S,OUT]

    const int  N   = in_sizes[2];                // 4096
    const long wsz = (long)in_sizes[1];
    const int  K   = (int)(wsz / N);             // 4096
    const long xsz = (long)in_sizes[0];
    const int  M   = (int)(xsz / K);             // 8192

    unsigned char* xq = (unsigned char*)d_ws;    // M*K e4m3 bytes
    unsigned char* wq = xq + (size_t)M * K;      // N*K e4m3 bytes

    quant_kernel<<<2048, 256, 0, stream>>>((const float4v*)x, (u32x4*)xq, xsz / 16,
                                           (const float4v*)w, (u32x4*)wq, wsz / 16, in_s);

    dim3 grid((M / BM) * (N / BN));              // 64*16 = 1024 blocks, %8==0
    gemm_kernel<<<grid, 256, 0, stream>>>(xq, wq, bias, in_s, w_s, out, M, N, K);
}